// Round 14
// baseline (266.868 us; speedup 1.0000x reference)
//
#include <hip/hip_runtime.h>

#define N_NODES 50000
#define N_EDGES 800000
#define SCAN_BLOCKS ((N_NODES + 255) / 256)   // 196
#define HIST_BLOCKS ((N_EDGES + 255) / 256)   // 3125
#define GEMM_BLOCKS ((N_NODES + 63) / 64)     // 782
#define FUSED_BLOCKS (5 * GEMM_BLOCKS)        // 3910: 4 hist-role + 1 gemm-role per 5

__device__ __forceinline__ float lrelu(float x) { return fmaxf(x, 0.2f * x); }
__device__ __forceinline__ float elu(float x) { return x > 0.f ? x : __expf(x) - 1.f; }

typedef float f32x2 __attribute__((ext_vector_type(2)));

// bf16 helpers: lo/hi halves of a uint holding 2 consecutive bf16 elements
__device__ __forceinline__ float bfl(unsigned u) { return __uint_as_float(u << 16); }
__device__ __forceinline__ float bfh(unsigned u) { return __uint_as_float(u & 0xffff0000u); }
__device__ __forceinline__ unsigned f2bf_rn(float x) {
  unsigned u = __float_as_uint(x);
  return (u + 0x7fffu + ((u >> 16) & 1u)) >> 16;
}
__device__ __forceinline__ unsigned pack2bf(float a, float b) {
  return f2bf_rn(a) | (f2bf_rn(b) << 16);
}

// ---------------- scan ----------------
__device__ __forceinline__ int block_excl_scan(int v, int* total_out) {
  int lane = threadIdx.x & 63;
  int wid = threadIdx.x >> 6;
  int x = v;
#pragma unroll
  for (int off = 1; off < 64; off <<= 1) {
    int u = __shfl_up(x, off);
    if (lane >= off) x += u;
  }
  __shared__ int wsum[4];
  if (lane == 63) wsum[wid] = x;
  __syncthreads();
  int add = 0;
#pragma unroll
  for (int k = 0; k < 4; ++k)
    if (k < wid) add += wsum[k];
  if (total_out) *total_out = wsum[0] + wsum[1] + wsum[2] + wsum[3];
  return x + add - v;
}

__global__ __launch_bounds__(256) void scan_part_kernel(const int* __restrict__ deg, int* __restrict__ rowptrP,
                                                        int* __restrict__ blocksum) {
  int g = blockIdx.x * 256 + threadIdx.x;
  int v = (g < N_NODES) ? deg[g] : 0;
  int total;
  int ex = block_excl_scan(v, &total);
  if (g < N_NODES) rowptrP[g] = ex;
  if (threadIdx.x == 0) blocksum[blockIdx.x] = total;
}

__global__ __launch_bounds__(256) void scan_top_kernel(const int* __restrict__ blocksum, int* __restrict__ blockoff) {
  int t = threadIdx.x;
  int v = (t < SCAN_BLOCKS) ? blocksum[t] : 0;
  int ex = block_excl_scan(v, nullptr);
  if (t < SCAN_BLOCKS) blockoff[t] = ex;
}

// scatter (edge blocks) + rowptr finalize (node blocks) in one dispatch.
// Edge part reads the immutable partial scan; node part writes the final
// rowptr to a separate array -> no RAW hazard.
__global__ __launch_bounds__(256) void scatter_kernel(const int* __restrict__ ei, const int* __restrict__ rowptrP,
                                                      const int* __restrict__ blockoff, const int* __restrict__ rank,
                                                      int* __restrict__ col, int* __restrict__ rowptrF) {
  if (blockIdx.x < HIST_BLOCKS) {
    int e = blockIdx.x * 256 + threadIdx.x;
    if (e < N_EDGES) {
      int d = ei[N_EDGES + e];
      col[rowptrP[d] + blockoff[d >> 8] + rank[e]] = ei[e];
    }
  } else {
    int g = (blockIdx.x - HIST_BLOCKS) * 256 + threadIdx.x;
    if (g < N_NODES) rowptrF[g] = rowptrP[g] + blockoff[g >> 8];
    if (g == 0) rowptrF[N_NODES] = N_EDGES;
  }
}

// ---------------- GEMM body + fused attention dots ----------------
// K staged in 4 phases of 32 rows; ws swizzled [k][c4][tx] (2-way, free);
// xs row stride 36 (2-way, free). LDS 25.6 KB for COLS=128.
#define XS_STRIDE 36
template <int COLS, bool ABF16>
__device__ __forceinline__ void gemm_body(int bx, const void* __restrict__ Ap, const float* __restrict__ W,
                                          const float* __restrict__ atts, const float* __restrict__ attd,
                                          unsigned* __restrict__ Yb, float* __restrict__ as_out,
                                          float* __restrict__ ad_out) {
  constexpr int CPT = COLS / 16;   // cols per thread (8 or 4)
  constexpr int G = COLS / 4;      // float4 groups per k-row (32 or 16)
  __shared__ float ws[32 * COLS];
  __shared__ float xs[64 * XS_STRIDE];
  int t = threadIdx.x;
  int rbase = bx * 64;
  int tx = t & 15, ty = t >> 4;
  float acc[4][CPT];
#pragma unroll
  for (int r = 0; r < 4; ++r)
#pragma unroll
    for (int c = 0; c < CPT; ++c) acc[r][c] = 0.f;

  const float4* W4 = (const float4*)W;
  float4* ws4 = (float4*)ws;
  for (int kt = 0; kt < 4; ++kt) {
    for (int i = t; i < 32 * G; i += 256) {
      int k = i / G;
      int g = i - k * G;
      int c4g = g & (CPT / 4 - 1);
      int txg = g / (CPT / 4);
      ws4[k * G + c4g * 16 + txg] = W4[kt * 32 * G + i];
    }
    if constexpr (ABF16) {
      const uint4* A4 = (const uint4*)Ap;  // row = 128 bf16 = 16 uint4; 4 per phase
      {
        int i = t;
        int row = i >> 2, q = i & 3;
        int gr = rbase + row; if (gr >= N_NODES) gr = N_NODES - 1;
        uint4 u = A4[gr * 16 + kt * 4 + q];
        float4 lo = make_float4(bfl(u.x), bfh(u.x), bfl(u.y), bfh(u.y));
        float4 hi = make_float4(bfl(u.z), bfh(u.z), bfl(u.w), bfh(u.w));
        float4* dst = (float4*)&xs[row * XS_STRIDE + q * 8];
        dst[0] = lo; dst[1] = hi;
      }
    } else {
      const float4* A4 = (const float4*)Ap;  // row = 32 float4; 8 per phase
      for (int i = t; i < 512; i += 256) {
        int row = i >> 3, kc = i & 7;
        int gr = rbase + row; if (gr >= N_NODES) gr = N_NODES - 1;
        *(float4*)&xs[row * XS_STRIDE + kc * 4] = A4[gr * 32 + kt * 8 + kc];
      }
    }
    __syncthreads();
#pragma unroll 8
    for (int k = 0; k < 32; ++k) {
      float xr[4];
#pragma unroll
      for (int r = 0; r < 4; ++r) xr[r] = xs[(ty * 4 + r) * XS_STRIDE + k];
#pragma unroll
      for (int c4 = 0; c4 < CPT / 4; ++c4) {
        float4 wv = ws4[k * G + c4 * 16 + tx];
#pragma unroll
        for (int r = 0; r < 4; ++r) {
          acc[r][c4 * 4 + 0] += xr[r] * wv.x;
          acc[r][c4 * 4 + 1] += xr[r] * wv.y;
          acc[r][c4 * 4 + 2] += xr[r] * wv.z;
          acc[r][c4 * 4 + 3] += xr[r] * wv.w;
        }
      }
    }
    __syncthreads();
  }

  // fused attention dots
  if constexpr (COLS == 128) {
    int h = tx >> 2;
    int base = h * 32 + (tx & 3) * 8;
#pragma unroll
    for (int r = 0; r < 4; ++r) {
      float ps = 0.f, pd = 0.f;
#pragma unroll
      for (int c = 0; c < 8; ++c) {
        ps += acc[r][c] * atts[base + c];
        pd += acc[r][c] * attd[base + c];
      }
      ps += __shfl_xor(ps, 1); pd += __shfl_xor(pd, 1);
      ps += __shfl_xor(ps, 2); pd += __shfl_xor(pd, 2);
      int row = rbase + ty * 4 + r;
      if ((tx & 3) == 0 && row < N_NODES) {
        as_out[row * 4 + h] = ps;
        ad_out[row * 4 + h] = pd;
      }
    }
  } else {
#pragma unroll
    for (int r = 0; r < 4; ++r) {
      float ps = 0.f, pd = 0.f;
#pragma unroll
      for (int c = 0; c < 4; ++c) {
        ps += acc[r][c] * atts[tx * 4 + c];
        pd += acc[r][c] * attd[tx * 4 + c];
      }
#pragma unroll
      for (int off = 1; off < 16; off <<= 1) {
        ps += __shfl_xor(ps, off);
        pd += __shfl_xor(pd, off);
      }
      int row = rbase + ty * 4 + r;
      if (tx == 0 && row < N_NODES) {
        as_out[row] = ps;
        ad_out[row] = pd;
      }
    }
  }

#pragma unroll
  for (int r = 0; r < 4; ++r) {
    int row = rbase + ty * 4 + r;
    if (row < N_NODES) {
      if constexpr (CPT == 8) {
        uint4 o;
        o.x = pack2bf(acc[r][0], acc[r][1]);
        o.y = pack2bf(acc[r][2], acc[r][3]);
        o.z = pack2bf(acc[r][4], acc[r][5]);
        o.w = pack2bf(acc[r][6], acc[r][7]);
        ((uint4*)Yb)[row * 16 + tx] = o;
      } else {
        uint2 o;
        o.x = pack2bf(acc[r][0], acc[r][1]);
        o.y = pack2bf(acc[r][2], acc[r][3]);
        ((uint2*)Yb)[row * 16 + tx] = o;
      }
    }
  }
}

// ---------------- fused hist + gemm128, roles interleaved 4:1 ----------------
__global__ __launch_bounds__(256) void gemm128_hist_kernel(const float* __restrict__ x, const float* __restrict__ W1,
                                                           const float* __restrict__ atts, const float* __restrict__ attd,
                                                           unsigned* __restrict__ h1b, float* __restrict__ as1,
                                                           float* __restrict__ ad1, const int* __restrict__ ei,
                                                           int* __restrict__ deg, int* __restrict__ rank) {
  int role = blockIdx.x % 5;
  int base = blockIdx.x / 5;
  if (role != 4) {
    int e = (base * 4 + role) * 256 + threadIdx.x;
    if (e < N_EDGES) rank[e] = atomicAdd(&deg[ei[N_EDGES + e]], 1);
    return;
  }
  gemm_body<128, false>(base, x, W1, atts, attd, h1b, as1, ad1);
}

__global__ __launch_bounds__(256) void gemm64_kernel(const unsigned* __restrict__ h1eb, const float* __restrict__ W2,
                                                     const float* __restrict__ atts, const float* __restrict__ attd,
                                                     unsigned* __restrict__ h2b, float* __restrict__ as2,
                                                     float* __restrict__ ad2) {
  gemm_body<64, true>(blockIdx.x, h1eb, W2, atts, attd, h2b, as2, ad2);
}

// ---------------- layer-1 gather, fused e-compute + denom; f32x2 packed FMA ----------------
__global__ __launch_bounds__(256) void agg1_kernel(const uint4* __restrict__ h1b4, const int* __restrict__ rowptr,
                                                   const int* __restrict__ col, const float* __restrict__ as1,
                                                   const float* __restrict__ ad1, const float4* __restrict__ b1v,
                                                   uint4* __restrict__ h1eb4) {
  int n = (blockIdx.x * 256 + threadIdx.x) >> 6;
  int lane = threadIdx.x & 63;
  int slot = lane >> 4;  // 0..3
  int fo = lane & 15;    // feats fo*8 .. fo*8+7
  int h = fo >> 2;       // head for these 8 feats
  int beg = rowptr[n], end = rowptr[n + 1];
  float adh = ad1[n * 4 + h];

  f32x2 acc2[4];
#pragma unroll
  for (int j = 0; j < 4; ++j) acc2[j] = (f32x2){0.f, 0.f};
  float esum = 0.f;

#define ACC_EDGE1(E)                                            \
  {                                                             \
    int src = col[E];                                           \
    float a = __expf(lrelu(as1[src * 4 + h] + adh));            \
    esum += a;                                                  \
    f32x2 av = {a, a};                                          \
    uint4 uu = h1b4[src * 16 + fo];                             \
    acc2[0] += av * (f32x2){bfl(uu.x), bfh(uu.x)};              \
    acc2[1] += av * (f32x2){bfl(uu.y), bfh(uu.y)};              \
    acc2[2] += av * (f32x2){bfl(uu.z), bfh(uu.z)};              \
    acc2[3] += av * (f32x2){bfl(uu.w), bfh(uu.w)};              \
  }

  int i = beg;
  for (; i + 16 <= end; i += 16) {
#pragma unroll
    for (int u = 0; u < 4; ++u) ACC_EDGE1(i + u * 4 + slot);
  }
  for (; i + 4 <= end; i += 4) ACC_EDGE1(i + slot);
  int rem = end - i;
  if (slot < rem) ACC_EDGE1(i + slot);
  // self loop (slot 0 only)
  if (slot == 0) {
    float a = __expf(lrelu(as1[n * 4 + h] + adh));
    esum += a;
    f32x2 av = {a, a};
    uint4 uu = h1b4[n * 16 + fo];
    acc2[0] += av * (f32x2){bfl(uu.x), bfh(uu.x)};
    acc2[1] += av * (f32x2){bfl(uu.y), bfh(uu.y)};
    acc2[2] += av * (f32x2){bfl(uu.z), bfh(uu.z)};
    acc2[3] += av * (f32x2){bfl(uu.w), bfh(uu.w)};
  }
#pragma unroll
  for (int j = 0; j < 4; ++j) {
    acc2[j].x += __shfl_xor(acc2[j].x, 16);
    acc2[j].y += __shfl_xor(acc2[j].y, 16);
    acc2[j].x += __shfl_xor(acc2[j].x, 32);
    acc2[j].y += __shfl_xor(acc2[j].y, 32);
  }
  esum += __shfl_xor(esum, 16);
  esum += __shfl_xor(esum, 32);
  if (slot == 0) {
    float dsc = 1.f / esum;
    float4 b0 = b1v[fo * 2], b1 = b1v[fo * 2 + 1];
    float f0 = elu(acc2[0].x * dsc + b0.x), f1 = elu(acc2[0].y * dsc + b0.y);
    float f2 = elu(acc2[1].x * dsc + b0.z), f3 = elu(acc2[1].y * dsc + b0.w);
    float f4 = elu(acc2[2].x * dsc + b1.x), f5 = elu(acc2[2].y * dsc + b1.y);
    float f6 = elu(acc2[3].x * dsc + b1.z), f7 = elu(acc2[3].y * dsc + b1.w);
    uint4 o;
    o.x = pack2bf(f0, f1); o.y = pack2bf(f2, f3);
    o.z = pack2bf(f4, f5); o.w = pack2bf(f6, f7);
    h1eb4[n * 16 + fo] = o;
  }
#undef ACC_EDGE1
}

// ---------------- layer-2 gather, fused e + denom + global add pool ----------------
__global__ __launch_bounds__(256) void agg2_kernel(const uint4* __restrict__ h2b4, const int* __restrict__ rowptr,
                                                   const int* __restrict__ col, const float* __restrict__ as2,
                                                   const float* __restrict__ ad2, const float4* __restrict__ b2v,
                                                   float* __restrict__ pooled) {
  __shared__ float red[4][64];
  int n = (blockIdx.x * 256 + threadIdx.x) >> 6;
  int lane = threadIdx.x & 63;
  int wid = threadIdx.x >> 6;
  int slot = lane >> 3;  // 0..7
  int fo = lane & 7;     // feats fo*8 .. fo*8+7
  int beg = rowptr[n], end = rowptr[n + 1];
  float ad = ad2[n];

  f32x2 acc2[4];
#pragma unroll
  for (int j = 0; j < 4; ++j) acc2[j] = (f32x2){0.f, 0.f};
  float esum = 0.f;

#define ACC_EDGE2(E)                                            \
  {                                                             \
    int src = col[E];                                           \
    float a = __expf(lrelu(as2[src] + ad));                     \
    esum += a;                                                  \
    f32x2 av = {a, a};                                          \
    uint4 uu = h2b4[src * 8 + fo];                              \
    acc2[0] += av * (f32x2){bfl(uu.x), bfh(uu.x)};              \
    acc2[1] += av * (f32x2){bfl(uu.y), bfh(uu.y)};              \
    acc2[2] += av * (f32x2){bfl(uu.z), bfh(uu.z)};              \
    acc2[3] += av * (f32x2){bfl(uu.w), bfh(uu.w)};              \
  }

  int i = beg;
  for (; i + 32 <= end; i += 32) {
#pragma unroll
    for (int u = 0; u < 4; ++u) ACC_EDGE2(i + u * 8 + slot);
  }
  for (; i + 8 <= end; i += 8) ACC_EDGE2(i + slot);
  int rem = end - i;
  if (slot < rem) ACC_EDGE2(i + slot);
  // self loop
  if (slot == 0) {
    float a = __expf(lrelu(as2[n] + ad));
    esum += a;
    f32x2 av = {a, a};
    uint4 uu = h2b4[n * 8 + fo];
    acc2[0] += av * (f32x2){bfl(uu.x), bfh(uu.x)};
    acc2[1] += av * (f32x2){bfl(uu.y), bfh(uu.y)};
    acc2[2] += av * (f32x2){bfl(uu.z), bfh(uu.z)};
    acc2[3] += av * (f32x2){bfl(uu.w), bfh(uu.w)};
  }
#pragma unroll
  for (int j = 0; j < 4; ++j) {
#pragma unroll
    for (int off = 8; off <= 32; off <<= 1) {
      acc2[j].x += __shfl_xor(acc2[j].x, off);
      acc2[j].y += __shfl_xor(acc2[j].y, off);
    }
  }
  esum += __shfl_xor(esum, 8);
  esum += __shfl_xor(esum, 16);
  esum += __shfl_xor(esum, 32);
  if (slot == 0) {
    float dsc = 1.f / esum;
    float4 b0 = b2v[fo * 2], b1 = b2v[fo * 2 + 1];
    red[wid][fo * 8 + 0] = elu(acc2[0].x * dsc + b0.x);
    red[wid][fo * 8 + 1] = elu(acc2[0].y * dsc + b0.y);
    red[wid][fo * 8 + 2] = elu(acc2[1].x * dsc + b0.z);
    red[wid][fo * 8 + 3] = elu(acc2[1].y * dsc + b0.w);
    red[wid][fo * 8 + 4] = elu(acc2[2].x * dsc + b1.x);
    red[wid][fo * 8 + 5] = elu(acc2[2].y * dsc + b1.y);
    red[wid][fo * 8 + 6] = elu(acc2[3].x * dsc + b1.z);
    red[wid][fo * 8 + 7] = elu(acc2[3].y * dsc + b1.w);
  }
  __syncthreads();
  if (threadIdx.x < 64) {
    float sum = red[0][threadIdx.x] + red[1][threadIdx.x] + red[2][threadIdx.x] + red[3][threadIdx.x];
    atomicAdd(&pooled[(blockIdx.x & 63) * 64 + threadIdx.x], sum);
  }
#undef ACC_EDGE2
}

// ---------------- final: reduce pooled stripes + pooled@Wl+bl ----------------
__global__ void final_kernel(const float* __restrict__ pooledS, const float* __restrict__ Wl,
                             const float* __restrict__ bl, float* __restrict__ out) {
  __shared__ float p[64];
  int t = threadIdx.x;
  float v = 0.f;
  for (int k = 0; k < 64; ++k) v += pooledS[k * 64 + t];
  p[t] = v;
  out[t] = v;
  __syncthreads();
  if (t < 2) {
    float s = bl[t];
    for (int k = 0; k < 64; ++k) s += p[k] * Wl[k * 2 + t];
    out[64 + t] = s;
  }
}

extern "C" void kernel_launch(void* const* d_in, const int* in_sizes, int n_in,
                              void* d_out, int out_size, void* d_ws, size_t ws_size,
                              hipStream_t stream) {
  (void)in_sizes; (void)n_in; (void)out_size; (void)ws_size;
  const float* x     = (const float*)d_in[0];
  const int*   ei    = (const int*)d_in[1];
  const float* W1    = (const float*)d_in[2];
  const float* atts1 = (const float*)d_in[3];
  const float* attd1 = (const float*)d_in[4];
  const float* b1    = (const float*)d_in[5];
  const float* W2    = (const float*)d_in[6];
  const float* atts2 = (const float*)d_in[7];
  const float* attd2 = (const float*)d_in[8];
  const float* b2    = (const float*)d_in[9];
  const float* Wl    = (const float*)d_in[10];
  const float* bl    = (const float*)d_in[11];
  float* out = (float*)d_out;

  char* w = (char*)d_ws;
  unsigned* h1b  = (unsigned*)w; w += (size_t)N_NODES * 128 * 2;  // 12.8 MB bf16
  unsigned* h1eb = (unsigned*)w; w += (size_t)N_NODES * 128 * 2;  // 12.8 MB bf16
  unsigned* h2b  = (unsigned*)w; w += (size_t)N_NODES * 64 * 2;   // 6.4 MB bf16
  float* as1  = (float*)w; w += (size_t)N_NODES * 16;
  float* ad1  = (float*)w; w += (size_t)N_NODES * 16;
  float* as2  = (float*)w; w += (size_t)N_NODES * 4;
  float* ad2  = (float*)w; w += (size_t)N_NODES * 4;
  int* deg    = (int*)w; w += (size_t)N_NODES * 4;
  float* pooled = (float*)w; w += 64 * 64 * 4;                    // 64 stripes x 64
  int* rowptrP = (int*)w; w += (size_t)(N_NODES + 1) * 4 + 12;
  int* rowptrF = (int*)w; w += (size_t)(N_NODES + 1) * 4 + 12;
  int* col    = (int*)w; w += (size_t)N_EDGES * 4;
  int* rank   = (int*)w; w += (size_t)N_EDGES * 4;
  int* blocksum = (int*)w; w += 256 * 4;
  int* blockoff = (int*)w; w += 256 * 4;

  // zero deg + pooled (contiguous)
  hipMemsetAsync(deg, 0, (size_t)N_NODES * 4 + 64 * 64 * 4, stream);

  // hist (atomic-bound) interleaved 4:1 with gemm128 (VALU/LDS-bound)
  gemm128_hist_kernel<<<FUSED_BLOCKS, 256, 0, stream>>>(x, W1, atts1, attd1, h1b, as1, ad1,
                                                        ei, deg, rank);
  scan_part_kernel<<<SCAN_BLOCKS, 256, 0, stream>>>(deg, rowptrP, blocksum);
  scan_top_kernel<<<1, 256, 0, stream>>>(blocksum, blockoff);
  scatter_kernel<<<HIST_BLOCKS + SCAN_BLOCKS, 256, 0, stream>>>(ei, rowptrP, blockoff, rank, col, rowptrF);

  agg1_kernel<<<N_NODES / 4, 256, 0, stream>>>((const uint4*)h1b, rowptrF, col, as1, ad1,
                                               (const float4*)b1, (uint4*)h1eb);

  gemm64_kernel<<<GEMM_BLOCKS, 256, 0, stream>>>(h1eb, W2, atts2, attd2, h2b, as2, ad2);
  agg2_kernel<<<N_NODES / 4, 256, 0, stream>>>((const uint4*)h2b, rowptrF, col, as2, ad2,
                                               (const float4*)b2, pooled);

  final_kernel<<<1, 64, 0, stream>>>(pooled, Wl, bl, out);
}

// Round 16
// 252.765 us; speedup vs baseline: 1.0558x; 1.0558x over previous
//
#include <hip/hip_runtime.h>

#define N_NODES 50000
#define N_EDGES 800000
#define SCAN_BLOCKS ((N_NODES + 255) / 256)   // 196
#define HIST_BLOCKS ((N_EDGES + 255) / 256)   // 3125
#define GEMM_BLOCKS ((N_NODES + 63) / 64)     // 782
#define FUSED_BLOCKS (5 * GEMM_BLOCKS)        // 3910: 4 hist-role + 1 gemm-role per 5

__device__ __forceinline__ float lrelu(float x) { return fmaxf(x, 0.2f * x); }
__device__ __forceinline__ float elu(float x) { return x > 0.f ? x : __expf(x) - 1.f; }

typedef float f32x2 __attribute__((ext_vector_type(2)));

// bf16 helpers (still used for h1e, which feeds gemm64)
__device__ __forceinline__ float bfl(unsigned u) { return __uint_as_float(u << 16); }
__device__ __forceinline__ float bfh(unsigned u) { return __uint_as_float(u & 0xffff0000u); }
__device__ __forceinline__ unsigned f2bf_rn(float x) {
  unsigned u = __float_as_uint(x);
  return (u + 0x7fffu + ((u >> 16) & 1u)) >> 16;
}
__device__ __forceinline__ unsigned pack2bf(float a, float b) {
  return f2bf_rn(a) | (f2bf_rn(b) << 16);
}

// ---------------- scan ----------------
__device__ __forceinline__ int block_excl_scan(int v, int* total_out) {
  int lane = threadIdx.x & 63;
  int wid = threadIdx.x >> 6;
  int x = v;
#pragma unroll
  for (int off = 1; off < 64; off <<= 1) {
    int u = __shfl_up(x, off);
    if (lane >= off) x += u;
  }
  __shared__ int wsum[4];
  if (lane == 63) wsum[wid] = x;
  __syncthreads();
  int add = 0;
#pragma unroll
  for (int k = 0; k < 4; ++k)
    if (k < wid) add += wsum[k];
  if (total_out) *total_out = wsum[0] + wsum[1] + wsum[2] + wsum[3];
  return x + add - v;
}

__global__ __launch_bounds__(256) void scan_part_kernel(const int* __restrict__ deg, int* __restrict__ rowptrP,
                                                        int* __restrict__ blocksum) {
  int g = blockIdx.x * 256 + threadIdx.x;
  int v = (g < N_NODES) ? deg[g] : 0;
  int total;
  int ex = block_excl_scan(v, &total);
  if (g < N_NODES) rowptrP[g] = ex;
  if (threadIdx.x == 0) blocksum[blockIdx.x] = total;
}

__global__ __launch_bounds__(256) void scan_top_kernel(const int* __restrict__ blocksum, int* __restrict__ blockoff) {
  int t = threadIdx.x;
  int v = (t < SCAN_BLOCKS) ? blocksum[t] : 0;
  int ex = block_excl_scan(v, nullptr);
  if (t < SCAN_BLOCKS) blockoff[t] = ex;
}

// scatter (edge blocks) + rowptr finalize (node blocks) in one dispatch.
__global__ __launch_bounds__(256) void scatter_kernel(const int* __restrict__ ei, const int* __restrict__ rowptrP,
                                                      const int* __restrict__ blockoff, const int* __restrict__ rank,
                                                      int* __restrict__ col, int* __restrict__ rowptrF) {
  if (blockIdx.x < HIST_BLOCKS) {
    int e = blockIdx.x * 256 + threadIdx.x;
    if (e < N_EDGES) {
      int d = ei[N_EDGES + e];
      col[rowptrP[d] + blockoff[d >> 8] + rank[e]] = ei[e];
    }
  } else {
    int g = (blockIdx.x - HIST_BLOCKS) * 256 + threadIdx.x;
    if (g < N_NODES) rowptrF[g] = rowptrP[g] + blockoff[g >> 8];
    if (g == 0) rowptrF[N_NODES] = N_EDGES;
  }
}

// ---------------- GEMM body + fused attention dots ----------------
// Output Yb stored as fp8 e4m3 (hardware pack). Attention dots from fp32 acc.
// K staged in 4 phases of 32 rows; ws swizzled [k][c4][tx] (2-way, free);
// xs row stride 36 (2-way, free). LDS 25.6 KB for COLS=128.
#define XS_STRIDE 36
template <int COLS, bool ABF16>
__device__ __forceinline__ void gemm_body(int bx, const void* __restrict__ Ap, const float* __restrict__ W,
                                          const float* __restrict__ atts, const float* __restrict__ attd,
                                          unsigned* __restrict__ Yb, float* __restrict__ as_out,
                                          float* __restrict__ ad_out) {
  constexpr int CPT = COLS / 16;   // cols per thread (8 or 4)
  constexpr int G = COLS / 4;      // float4 groups per k-row (32 or 16)
  __shared__ float ws[32 * COLS];
  __shared__ float xs[64 * XS_STRIDE];
  int t = threadIdx.x;
  int rbase = bx * 64;
  int tx = t & 15, ty = t >> 4;
  float acc[4][CPT];
#pragma unroll
  for (int r = 0; r < 4; ++r)
#pragma unroll
    for (int c = 0; c < CPT; ++c) acc[r][c] = 0.f;

  const float4* W4 = (const float4*)W;
  float4* ws4 = (float4*)ws;
  for (int kt = 0; kt < 4; ++kt) {
    for (int i = t; i < 32 * G; i += 256) {
      int k = i / G;
      int g = i - k * G;
      int c4g = g & (CPT / 4 - 1);
      int txg = g / (CPT / 4);
      ws4[k * G + c4g * 16 + txg] = W4[kt * 32 * G + i];
    }
    if constexpr (ABF16) {
      const uint4* A4 = (const uint4*)Ap;  // row = 128 bf16 = 16 uint4; 4 per phase
      {
        int i = t;
        int row = i >> 2, q = i & 3;
        int gr = rbase + row; if (gr >= N_NODES) gr = N_NODES - 1;
        uint4 u = A4[gr * 16 + kt * 4 + q];
        float4 lo = make_float4(bfl(u.x), bfh(u.x), bfl(u.y), bfh(u.y));
        float4 hi = make_float4(bfl(u.z), bfh(u.z), bfl(u.w), bfh(u.w));
        float4* dst = (float4*)&xs[row * XS_STRIDE + q * 8];
        dst[0] = lo; dst[1] = hi;
      }
    } else {
      const float4* A4 = (const float4*)Ap;  // row = 32 float4; 8 per phase
      for (int i = t; i < 512; i += 256) {
        int row = i >> 3, kc = i & 7;
        int gr = rbase + row; if (gr >= N_NODES) gr = N_NODES - 1;
        *(float4*)&xs[row * XS_STRIDE + kc * 4] = A4[gr * 32 + kt * 8 + kc];
      }
    }
    __syncthreads();
#pragma unroll 8
    for (int k = 0; k < 32; ++k) {
      float xr[4];
#pragma unroll
      for (int r = 0; r < 4; ++r) xr[r] = xs[(ty * 4 + r) * XS_STRIDE + k];
#pragma unroll
      for (int c4 = 0; c4 < CPT / 4; ++c4) {
        float4 wv = ws4[k * G + c4 * 16 + tx];
#pragma unroll
        for (int r = 0; r < 4; ++r) {
          acc[r][c4 * 4 + 0] += xr[r] * wv.x;
          acc[r][c4 * 4 + 1] += xr[r] * wv.y;
          acc[r][c4 * 4 + 2] += xr[r] * wv.z;
          acc[r][c4 * 4 + 3] += xr[r] * wv.w;
        }
      }
    }
    __syncthreads();
  }

  // fused attention dots (from fp32 accumulators)
  if constexpr (COLS == 128) {
    int h = tx >> 2;
    int base = h * 32 + (tx & 3) * 8;
#pragma unroll
    for (int r = 0; r < 4; ++r) {
      float ps = 0.f, pd = 0.f;
#pragma unroll
      for (int c = 0; c < 8; ++c) {
        ps += acc[r][c] * atts[base + c];
        pd += acc[r][c] * attd[base + c];
      }
      ps += __shfl_xor(ps, 1); pd += __shfl_xor(pd, 1);
      ps += __shfl_xor(ps, 2); pd += __shfl_xor(pd, 2);
      int row = rbase + ty * 4 + r;
      if ((tx & 3) == 0 && row < N_NODES) {
        as_out[row * 4 + h] = ps;
        ad_out[row * 4 + h] = pd;
      }
    }
  } else {
#pragma unroll
    for (int r = 0; r < 4; ++r) {
      float ps = 0.f, pd = 0.f;
#pragma unroll
      for (int c = 0; c < 4; ++c) {
        ps += acc[r][c] * atts[tx * 4 + c];
        pd += acc[r][c] * attd[tx * 4 + c];
      }
#pragma unroll
      for (int off = 1; off < 16; off <<= 1) {
        ps += __shfl_xor(ps, off);
        pd += __shfl_xor(pd, off);
      }
      int row = rbase + ty * 4 + r;
      if (tx == 0 && row < N_NODES) {
        as_out[row] = ps;
        ad_out[row] = pd;
      }
    }
  }

  // fp8 e4m3 store
#pragma unroll
  for (int r = 0; r < 4; ++r) {
    int row = rbase + ty * 4 + r;
    if (row < N_NODES) {
      if constexpr (CPT == 8) {
        unsigned lo = __builtin_amdgcn_cvt_pk_fp8_f32(acc[r][0], acc[r][1], 0, false);
        lo = __builtin_amdgcn_cvt_pk_fp8_f32(acc[r][2], acc[r][3], lo, true);
        unsigned hi = __builtin_amdgcn_cvt_pk_fp8_f32(acc[r][4], acc[r][5], 0, false);
        hi = __builtin_amdgcn_cvt_pk_fp8_f32(acc[r][6], acc[r][7], hi, true);
        ((uint2*)Yb)[row * 16 + tx] = make_uint2(lo, hi);  // row = 128 fp8 = 16 uint2
      } else {
        unsigned u = __builtin_amdgcn_cvt_pk_fp8_f32(acc[r][0], acc[r][1], 0, false);
        u = __builtin_amdgcn_cvt_pk_fp8_f32(acc[r][2], acc[r][3], u, true);
        Yb[row * 16 + tx] = u;  // row = 64 fp8 = 16 uint
      }
    }
  }
}

// ---------------- fused hist + gemm128, roles interleaved 4:1 ----------------
__global__ __launch_bounds__(256) void gemm128_hist_kernel(const float* __restrict__ x, const float* __restrict__ W1,
                                                           const float* __restrict__ atts, const float* __restrict__ attd,
                                                           unsigned* __restrict__ h1b, float* __restrict__ as1,
                                                           float* __restrict__ ad1, const int* __restrict__ ei,
                                                           int* __restrict__ deg, int* __restrict__ rank) {
  int role = blockIdx.x % 5;
  int base = blockIdx.x / 5;
  if (role != 4) {
    int e = (base * 4 + role) * 256 + threadIdx.x;
    if (e < N_EDGES) rank[e] = atomicAdd(&deg[ei[N_EDGES + e]], 1);
    return;
  }
  gemm_body<128, false>(base, x, W1, atts, attd, h1b, as1, ad1);
}

__global__ __launch_bounds__(256) void gemm64_kernel(const unsigned* __restrict__ h1eb, const float* __restrict__ W2,
                                                     const float* __restrict__ atts, const float* __restrict__ attd,
                                                     unsigned* __restrict__ h2b, float* __restrict__ as2,
                                                     float* __restrict__ ad2) {
  gemm_body<64, true>(blockIdx.x, h1eb, W2, atts, attd, h2b, as2, ad2);
}

// ---------------- layer-1 gather, fused e-compute + denom; fp8 rows ----------------
__global__ __launch_bounds__(256) void agg1_kernel(const uint2* __restrict__ h1f8, const int* __restrict__ rowptr,
                                                   const int* __restrict__ col, const float* __restrict__ as1,
                                                   const float* __restrict__ ad1, const float4* __restrict__ b1v,
                                                   uint4* __restrict__ h1eb4) {
  int n = (blockIdx.x * 256 + threadIdx.x) >> 6;
  int lane = threadIdx.x & 63;
  int slot = lane >> 4;  // 0..3
  int fo = lane & 15;    // feats fo*8 .. fo*8+7
  int h = fo >> 2;       // head for these 8 feats
  int beg = rowptr[n], end = rowptr[n + 1];
  float adh = ad1[n * 4 + h];

  f32x2 acc2[4];
#pragma unroll
  for (int j = 0; j < 4; ++j) acc2[j] = (f32x2){0.f, 0.f};
  float esum = 0.f;

#define ACC_EDGE1(E)                                               \
  {                                                                \
    int src = col[E];                                              \
    float a = __expf(lrelu(as1[src * 4 + h] + adh));               \
    esum += a;                                                     \
    f32x2 av = {a, a};                                             \
    uint2 uu = h1f8[src * 16 + fo];                                \
    f32x2 p0 = __builtin_amdgcn_cvt_pk_f32_fp8(uu.x, false);       \
    f32x2 p1 = __builtin_amdgcn_cvt_pk_f32_fp8(uu.x, true);        \
    f32x2 p2 = __builtin_amdgcn_cvt_pk_f32_fp8(uu.y, false);       \
    f32x2 p3 = __builtin_amdgcn_cvt_pk_f32_fp8(uu.y, true);        \
    acc2[0] += av * p0; acc2[1] += av * p1;                        \
    acc2[2] += av * p2; acc2[3] += av * p3;                        \
  }

  int i = beg;
  for (; i + 16 <= end; i += 16) {
#pragma unroll
    for (int u = 0; u < 4; ++u) ACC_EDGE1(i + u * 4 + slot);
  }
  for (; i + 4 <= end; i += 4) ACC_EDGE1(i + slot);
  int rem = end - i;
  if (slot < rem) ACC_EDGE1(i + slot);
#undef ACC_EDGE1
  // self loop (slot 0 only)
  if (slot == 0) {
    float a = __expf(lrelu(as1[n * 4 + h] + adh));
    esum += a;
    f32x2 av = {a, a};
    uint2 uu = h1f8[n * 16 + fo];
    f32x2 p0 = __builtin_amdgcn_cvt_pk_f32_fp8(uu.x, false);
    f32x2 p1 = __builtin_amdgcn_cvt_pk_f32_fp8(uu.x, true);
    f32x2 p2 = __builtin_amdgcn_cvt_pk_f32_fp8(uu.y, false);
    f32x2 p3 = __builtin_amdgcn_cvt_pk_f32_fp8(uu.y, true);
    acc2[0] += av * p0; acc2[1] += av * p1;
    acc2[2] += av * p2; acc2[3] += av * p3;
  }
#pragma unroll
  for (int j = 0; j < 4; ++j) {
    acc2[j].x += __shfl_xor(acc2[j].x, 16);
    acc2[j].y += __shfl_xor(acc2[j].y, 16);
    acc2[j].x += __shfl_xor(acc2[j].x, 32);
    acc2[j].y += __shfl_xor(acc2[j].y, 32);
  }
  esum += __shfl_xor(esum, 16);
  esum += __shfl_xor(esum, 32);
  if (slot == 0) {
    float dsc = 1.f / esum;
    float4 b0 = b1v[fo * 2], b1 = b1v[fo * 2 + 1];
    float f0 = elu(acc2[0].x * dsc + b0.x), f1 = elu(acc2[0].y * dsc + b0.y);
    float f2 = elu(acc2[1].x * dsc + b0.z), f3 = elu(acc2[1].y * dsc + b0.w);
    float f4 = elu(acc2[2].x * dsc + b1.x), f5 = elu(acc2[2].y * dsc + b1.y);
    float f6 = elu(acc2[3].x * dsc + b1.z), f7 = elu(acc2[3].y * dsc + b1.w);
    uint4 o;
    o.x = pack2bf(f0, f1); o.y = pack2bf(f2, f3);
    o.z = pack2bf(f4, f5); o.w = pack2bf(f6, f7);
    h1eb4[n * 16 + fo] = o;  // h1e stays bf16 (feeds gemm64)
  }
}

// ---------------- layer-2 gather, fused e + denom + global add pool; fp8 rows ----------------
__global__ __launch_bounds__(256) void agg2_kernel(const uint2* __restrict__ h2f8, const int* __restrict__ rowptr,
                                                   const int* __restrict__ col, const float* __restrict__ as2,
                                                   const float* __restrict__ ad2, const float4* __restrict__ b2v,
                                                   float* __restrict__ pooled) {
  __shared__ float red[4][64];
  int n = (blockIdx.x * 256 + threadIdx.x) >> 6;
  int lane = threadIdx.x & 63;
  int wid = threadIdx.x >> 6;
  int slot = lane >> 3;  // 0..7
  int fo = lane & 7;     // feats fo*8 .. fo*8+7
  int beg = rowptr[n], end = rowptr[n + 1];
  float ad = ad2[n];

  f32x2 acc2[4];
#pragma unroll
  for (int j = 0; j < 4; ++j) acc2[j] = (f32x2){0.f, 0.f};
  float esum = 0.f;

#define ACC_EDGE2(E)                                               \
  {                                                                \
    int src = col[E];                                              \
    float a = __expf(lrelu(as2[src] + ad));                        \
    esum += a;                                                     \
    f32x2 av = {a, a};                                             \
    uint2 uu = h2f8[src * 8 + fo];                                 \
    f32x2 p0 = __builtin_amdgcn_cvt_pk_f32_fp8(uu.x, false);       \
    f32x2 p1 = __builtin_amdgcn_cvt_pk_f32_fp8(uu.x, true);        \
    f32x2 p2 = __builtin_amdgcn_cvt_pk_f32_fp8(uu.y, false);       \
    f32x2 p3 = __builtin_amdgcn_cvt_pk_f32_fp8(uu.y, true);        \
    acc2[0] += av * p0; acc2[1] += av * p1;                        \
    acc2[2] += av * p2; acc2[3] += av * p3;                        \
  }

  int i = beg;
  for (; i + 32 <= end; i += 32) {
#pragma unroll
    for (int u = 0; u < 4; ++u) ACC_EDGE2(i + u * 8 + slot);
  }
  for (; i + 8 <= end; i += 8) ACC_EDGE2(i + slot);
  int rem = end - i;
  if (slot < rem) ACC_EDGE2(i + slot);
#undef ACC_EDGE2
  // self loop
  if (slot == 0) {
    float a = __expf(lrelu(as2[n] + ad));
    esum += a;
    f32x2 av = {a, a};
    uint2 uu = h2f8[n * 8 + fo];
    f32x2 p0 = __builtin_amdgcn_cvt_pk_f32_fp8(uu.x, false);
    f32x2 p1 = __builtin_amdgcn_cvt_pk_f32_fp8(uu.x, true);
    f32x2 p2 = __builtin_amdgcn_cvt_pk_f32_fp8(uu.y, false);
    f32x2 p3 = __builtin_amdgcn_cvt_pk_f32_fp8(uu.y, true);
    acc2[0] += av * p0; acc2[1] += av * p1;
    acc2[2] += av * p2; acc2[3] += av * p3;
  }
#pragma unroll
  for (int j = 0; j < 4; ++j) {
#pragma unroll
    for (int off = 8; off <= 32; off <<= 1) {
      acc2[j].x += __shfl_xor(acc2[j].x, off);
      acc2[j].y += __shfl_xor(acc2[j].y, off);
    }
  }
  esum += __shfl_xor(esum, 8);
  esum += __shfl_xor(esum, 16);
  esum += __shfl_xor(esum, 32);
  if (slot == 0) {
    float dsc = 1.f / esum;
    float4 b0 = b2v[fo * 2], b1 = b2v[fo * 2 + 1];
    red[wid][fo * 8 + 0] = elu(acc2[0].x * dsc + b0.x);
    red[wid][fo * 8 + 1] = elu(acc2[0].y * dsc + b0.y);
    red[wid][fo * 8 + 2] = elu(acc2[1].x * dsc + b0.z);
    red[wid][fo * 8 + 3] = elu(acc2[1].y * dsc + b0.w);
    red[wid][fo * 8 + 4] = elu(acc2[2].x * dsc + b1.x);
    red[wid][fo * 8 + 5] = elu(acc2[2].y * dsc + b1.y);
    red[wid][fo * 8 + 6] = elu(acc2[3].x * dsc + b1.z);
    red[wid][fo * 8 + 7] = elu(acc2[3].y * dsc + b1.w);
  }
  __syncthreads();
  if (threadIdx.x < 64) {
    float sum = red[0][threadIdx.x] + red[1][threadIdx.x] + red[2][threadIdx.x] + red[3][threadIdx.x];
    atomicAdd(&pooled[(blockIdx.x & 63) * 64 + threadIdx.x], sum);
  }
}

// ---------------- final: reduce pooled stripes + pooled@Wl+bl ----------------
__global__ void final_kernel(const float* __restrict__ pooledS, const float* __restrict__ Wl,
                             const float* __restrict__ bl, float* __restrict__ out) {
  __shared__ float p[64];
  int t = threadIdx.x;
  float v = 0.f;
  for (int k = 0; k < 64; ++k) v += pooledS[k * 64 + t];
  p[t] = v;
  out[t] = v;
  __syncthreads();
  if (t < 2) {
    float s = bl[t];
    for (int k = 0; k < 64; ++k) s += p[k] * Wl[k * 2 + t];
    out[64 + t] = s;
  }
}

extern "C" void kernel_launch(void* const* d_in, const int* in_sizes, int n_in,
                              void* d_out, int out_size, void* d_ws, size_t ws_size,
                              hipStream_t stream) {
  (void)in_sizes; (void)n_in; (void)out_size; (void)ws_size;
  const float* x     = (const float*)d_in[0];
  const int*   ei    = (const int*)d_in[1];
  const float* W1    = (const float*)d_in[2];
  const float* atts1 = (const float*)d_in[3];
  const float* attd1 = (const float*)d_in[4];
  const float* b1    = (const float*)d_in[5];
  const float* W2    = (const float*)d_in[6];
  const float* atts2 = (const float*)d_in[7];
  const float* attd2 = (const float*)d_in[8];
  const float* b2    = (const float*)d_in[9];
  const float* Wl    = (const float*)d_in[10];
  const float* bl    = (const float*)d_in[11];
  float* out = (float*)d_out;

  char* w = (char*)d_ws;
  unsigned* h1b  = (unsigned*)w; w += (size_t)N_NODES * 128;      // 6.4 MB fp8
  unsigned* h1eb = (unsigned*)w; w += (size_t)N_NODES * 128 * 2;  // 12.8 MB bf16
  unsigned* h2b  = (unsigned*)w; w += (size_t)N_NODES * 64;       // 3.2 MB fp8
  float* as1  = (float*)w; w += (size_t)N_NODES * 16;
  float* ad1  = (float*)w; w += (size_t)N_NODES * 16;
  float* as2  = (float*)w; w += (size_t)N_NODES * 4;
  float* ad2  = (float*)w; w += (size_t)N_NODES * 4;
  int* deg    = (int*)w; w += (size_t)N_NODES * 4;
  float* pooled = (float*)w; w += 64 * 64 * 4;                    // 64 stripes x 64
  int* rowptrP = (int*)w; w += (size_t)(N_NODES + 1) * 4 + 12;
  int* rowptrF = (int*)w; w += (size_t)(N_NODES + 1) * 4 + 12;
  int* col    = (int*)w; w += (size_t)N_EDGES * 4;
  int* rank   = (int*)w; w += (size_t)N_EDGES * 4;
  int* blocksum = (int*)w; w += 256 * 4;
  int* blockoff = (int*)w; w += 256 * 4;

  // zero deg + pooled (contiguous)
  (void)hipMemsetAsync(deg, 0, (size_t)N_NODES * 4 + 64 * 64 * 4, stream);

  // hist (atomic-bound) interleaved 4:1 with gemm128 (VALU/LDS-bound)
  gemm128_hist_kernel<<<FUSED_BLOCKS, 256, 0, stream>>>(x, W1, atts1, attd1, h1b, as1, ad1,
                                                        ei, deg, rank);
  scan_part_kernel<<<SCAN_BLOCKS, 256, 0, stream>>>(deg, rowptrP, blocksum);
  scan_top_kernel<<<1, 256, 0, stream>>>(blocksum, blockoff);
  scatter_kernel<<<HIST_BLOCKS + SCAN_BLOCKS, 256, 0, stream>>>(ei, rowptrP, blockoff, rank, col, rowptrF);

  agg1_kernel<<<N_NODES / 4, 256, 0, stream>>>((const uint2*)h1b, rowptrF, col, as1, ad1,
                                               (const float4*)b1, (uint4*)h1eb);

  gemm64_kernel<<<GEMM_BLOCKS, 256, 0, stream>>>(h1eb, W2, atts2, attd2, h2b, as2, ad2);
  agg2_kernel<<<N_NODES / 4, 256, 0, stream>>>((const uint2*)h2b, rowptrF, col, as2, ad2,
                                               (const float4*)b2, pooled);

  final_kernel<<<1, 64, 0, stream>>>(pooled, Wl, bl, out);
}

// Round 17
// 230.770 us; speedup vs baseline: 1.1564x; 1.0953x over previous
//
#include <hip/hip_runtime.h>

#define N_NODES 50000
#define N_EDGES 800000
#define NB 196                        // buckets = ceil(50000/256)
#define P1_BLOCKS 256                 // pass-1/2 blocks
#define EPB 3125                      // edges per block (256*3125 = 800000)
#define BH_SIZE (NB * P1_BLOCKS)      // 50176 = 196 scan-blocks of 256
#define GEMM_BLOCKS ((N_NODES + 63) / 64)     // 782

__device__ __forceinline__ float lrelu(float x) { return fmaxf(x, 0.2f * x); }
__device__ __forceinline__ float elu(float x) { return x > 0.f ? x : __expf(x) - 1.f; }

typedef float f32x2 __attribute__((ext_vector_type(2)));

// bf16 helpers (h1e feeds gemm64)
__device__ __forceinline__ float bfl(unsigned u) { return __uint_as_float(u << 16); }
__device__ __forceinline__ float bfh(unsigned u) { return __uint_as_float(u & 0xffff0000u); }
__device__ __forceinline__ unsigned f2bf_rn(float x) {
  unsigned u = __float_as_uint(x);
  return (u + 0x7fffu + ((u >> 16) & 1u)) >> 16;
}
__device__ __forceinline__ unsigned pack2bf(float a, float b) {
  return f2bf_rn(a) | (f2bf_rn(b) << 16);
}

__device__ __forceinline__ int block_excl_scan(int v, int* total_out) {
  int lane = threadIdx.x & 63;
  int wid = threadIdx.x >> 6;
  int x = v;
#pragma unroll
  for (int off = 1; off < 64; off <<= 1) {
    int u = __shfl_up(x, off);
    if (lane >= off) x += u;
  }
  __shared__ int wsum[4];
  if (lane == 63) wsum[wid] = x;
  __syncthreads();
  int add = 0;
#pragma unroll
  for (int k = 0; k < 4; ++k)
    if (k < wid) add += wsum[k];
  if (total_out) *total_out = wsum[0] + wsum[1] + wsum[2] + wsum[3];
  return x + add - v;
}

// ---------------- CSR build via 2-level LDS counting sort (no global atomics) ----------------
// Pass 1: per-block LDS histogram of coarse bucket (dst>>8)
__global__ __launch_bounds__(256) void hist1_kernel(const int* __restrict__ ei, int* __restrict__ bh) {
  __shared__ int cnt[NB];
  for (int t = threadIdx.x; t < NB; t += 256) cnt[t] = 0;
  __syncthreads();
  int start = blockIdx.x * EPB;
  for (int i = start + threadIdx.x; i < start + EPB; i += 256)
    atomicAdd(&cnt[ei[N_EDGES + i] >> 8], 1);
  __syncthreads();
  for (int t = threadIdx.x; t < NB; t += 256)
    bh[t * P1_BLOCKS + blockIdx.x] = cnt[t];
}

// scan over bh (bucket-major): partial within 256-blocks + top scan of block sums
__global__ __launch_bounds__(256) void scan_part_kernel(const int* __restrict__ bh, int* __restrict__ bhP,
                                                        int* __restrict__ blocksum) {
  int g = blockIdx.x * 256 + threadIdx.x;
  int v = bh[g];  // BH_SIZE divisible by 256
  int total;
  int ex = block_excl_scan(v, &total);
  bhP[g] = ex;
  if (threadIdx.x == 0) blocksum[blockIdx.x] = total;
}

__global__ __launch_bounds__(256) void scan_top_kernel(const int* __restrict__ blocksum, int* __restrict__ blockoff) {
  int t = threadIdx.x;
  int v = (t < NB) ? blocksum[t] : 0;
  int ex = block_excl_scan(v, nullptr);
  if (t < NB) blockoff[t] = ex;
}

// Pass 2: scatter edges into bucket order; rank within (block,bucket) from LDS cursor
__global__ __launch_bounds__(256) void scatter1_kernel(const int* __restrict__ ei, const int* __restrict__ bhP,
                                                       const int* __restrict__ blockoff, int2* __restrict__ eb) {
  __shared__ int cur[NB];
  for (int t = threadIdx.x; t < NB; t += 256) cur[t] = 0;
  __syncthreads();
  int start = blockIdx.x * EPB;
  for (int i = start + threadIdx.x; i < start + EPB; i += 256) {
    int dst = ei[N_EDGES + i];
    int src = ei[i];
    int bin = dst >> 8;
    int r = atomicAdd(&cur[bin], 1);
    int idx = bin * P1_BLOCKS + blockIdx.x;        // idx>>8 == bin
    int pos = bhP[idx] + blockoff[bin] + r;
    eb[pos] = make_int2(src, dst);
  }
}

// Pass 3: per-bucket fine sort (dst&255) -> rowptrF + final col
__global__ __launch_bounds__(256) void bucket_csr_kernel(const int2* __restrict__ eb, const int* __restrict__ blockoff,
                                                         int* __restrict__ rowptrF, int* __restrict__ col) {
  __shared__ int cnt[256];
  __shared__ int basel[256];
  __shared__ int cur[256];
  int b = blockIdx.x;
  int t = threadIdx.x;
  cnt[t] = 0;
  cur[t] = 0;
  __syncthreads();
  int start = blockoff[b];
  int end = (b == NB - 1) ? N_EDGES : blockoff[b + 1];
  for (int i = start + t; i < end; i += 256)
    atomicAdd(&cnt[eb[i].y & 255], 1);
  __syncthreads();
  int ex = block_excl_scan(cnt[t], nullptr);
  basel[t] = start + ex;
  int g = b * 256 + t;
  if (g < N_NODES) rowptrF[g] = start + ex;
  if (g == N_NODES) rowptrF[N_NODES] = N_EDGES;
  __syncthreads();
  for (int i = start + t; i < end; i += 256) {
    int2 e = eb[i];
    int d8 = e.y & 255;
    int r = atomicAdd(&cur[d8], 1);
    col[basel[d8] + r] = e.x;
  }
}

// ---------------- GEMM body + fused attention dots ----------------
// Output Yb stored as fp8 e4m3 (hardware pack). Attention dots from fp32 acc.
// K staged in 4 phases of 32 rows; ws swizzled [k][c4][tx] (2-way, free);
// xs row stride 36 (2-way, free). LDS 25.6 KB for COLS=128.
#define XS_STRIDE 36
template <int COLS, bool ABF16>
__device__ __forceinline__ void gemm_body(int bx, const void* __restrict__ Ap, const float* __restrict__ W,
                                          const float* __restrict__ atts, const float* __restrict__ attd,
                                          unsigned* __restrict__ Yb, float* __restrict__ as_out,
                                          float* __restrict__ ad_out) {
  constexpr int CPT = COLS / 16;   // cols per thread (8 or 4)
  constexpr int G = COLS / 4;      // float4 groups per k-row (32 or 16)
  __shared__ float ws[32 * COLS];
  __shared__ float xs[64 * XS_STRIDE];
  int t = threadIdx.x;
  int rbase = bx * 64;
  int tx = t & 15, ty = t >> 4;
  float acc[4][CPT];
#pragma unroll
  for (int r = 0; r < 4; ++r)
#pragma unroll
    for (int c = 0; c < CPT; ++c) acc[r][c] = 0.f;

  const float4* W4 = (const float4*)W;
  float4* ws4 = (float4*)ws;
  for (int kt = 0; kt < 4; ++kt) {
    for (int i = t; i < 32 * G; i += 256) {
      int k = i / G;
      int g = i - k * G;
      int c4g = g & (CPT / 4 - 1);
      int txg = g / (CPT / 4);
      ws4[k * G + c4g * 16 + txg] = W4[kt * 32 * G + i];
    }
    if constexpr (ABF16) {
      const uint4* A4 = (const uint4*)Ap;  // row = 128 bf16 = 16 uint4; 4 per phase
      {
        int i = t;
        int row = i >> 2, q = i & 3;
        int gr = rbase + row; if (gr >= N_NODES) gr = N_NODES - 1;
        uint4 u = A4[gr * 16 + kt * 4 + q];
        float4 lo = make_float4(bfl(u.x), bfh(u.x), bfl(u.y), bfh(u.y));
        float4 hi = make_float4(bfl(u.z), bfh(u.z), bfl(u.w), bfh(u.w));
        float4* dst = (float4*)&xs[row * XS_STRIDE + q * 8];
        dst[0] = lo; dst[1] = hi;
      }
    } else {
      const float4* A4 = (const float4*)Ap;  // row = 32 float4; 8 per phase
      for (int i = t; i < 512; i += 256) {
        int row = i >> 3, kc = i & 7;
        int gr = rbase + row; if (gr >= N_NODES) gr = N_NODES - 1;
        *(float4*)&xs[row * XS_STRIDE + kc * 4] = A4[gr * 32 + kt * 8 + kc];
      }
    }
    __syncthreads();
#pragma unroll 8
    for (int k = 0; k < 32; ++k) {
      float xr[4];
#pragma unroll
      for (int r = 0; r < 4; ++r) xr[r] = xs[(ty * 4 + r) * XS_STRIDE + k];
#pragma unroll
      for (int c4 = 0; c4 < CPT / 4; ++c4) {
        float4 wv = ws4[k * G + c4 * 16 + tx];
#pragma unroll
        for (int r = 0; r < 4; ++r) {
          acc[r][c4 * 4 + 0] += xr[r] * wv.x;
          acc[r][c4 * 4 + 1] += xr[r] * wv.y;
          acc[r][c4 * 4 + 2] += xr[r] * wv.z;
          acc[r][c4 * 4 + 3] += xr[r] * wv.w;
        }
      }
    }
    __syncthreads();
  }

  // fused attention dots (from fp32 accumulators)
  if constexpr (COLS == 128) {
    int h = tx >> 2;
    int base = h * 32 + (tx & 3) * 8;
#pragma unroll
    for (int r = 0; r < 4; ++r) {
      float ps = 0.f, pd = 0.f;
#pragma unroll
      for (int c = 0; c < 8; ++c) {
        ps += acc[r][c] * atts[base + c];
        pd += acc[r][c] * attd[base + c];
      }
      ps += __shfl_xor(ps, 1); pd += __shfl_xor(pd, 1);
      ps += __shfl_xor(ps, 2); pd += __shfl_xor(pd, 2);
      int row = rbase + ty * 4 + r;
      if ((tx & 3) == 0 && row < N_NODES) {
        as_out[row * 4 + h] = ps;
        ad_out[row * 4 + h] = pd;
      }
    }
  } else {
#pragma unroll
    for (int r = 0; r < 4; ++r) {
      float ps = 0.f, pd = 0.f;
#pragma unroll
      for (int c = 0; c < 4; ++c) {
        ps += acc[r][c] * atts[tx * 4 + c];
        pd += acc[r][c] * attd[tx * 4 + c];
      }
#pragma unroll
      for (int off = 1; off < 16; off <<= 1) {
        ps += __shfl_xor(ps, off);
        pd += __shfl_xor(pd, off);
      }
      int row = rbase + ty * 4 + r;
      if (tx == 0 && row < N_NODES) {
        as_out[row] = ps;
        ad_out[row] = pd;
      }
    }
  }

  // fp8 e4m3 store
#pragma unroll
  for (int r = 0; r < 4; ++r) {
    int row = rbase + ty * 4 + r;
    if (row < N_NODES) {
      if constexpr (CPT == 8) {
        unsigned lo = __builtin_amdgcn_cvt_pk_fp8_f32(acc[r][0], acc[r][1], 0, false);
        lo = __builtin_amdgcn_cvt_pk_fp8_f32(acc[r][2], acc[r][3], lo, true);
        unsigned hi = __builtin_amdgcn_cvt_pk_fp8_f32(acc[r][4], acc[r][5], 0, false);
        hi = __builtin_amdgcn_cvt_pk_fp8_f32(acc[r][6], acc[r][7], hi, true);
        ((uint2*)Yb)[row * 16 + tx] = make_uint2(lo, hi);  // row = 128 fp8 = 16 uint2
      } else {
        unsigned u = __builtin_amdgcn_cvt_pk_fp8_f32(acc[r][0], acc[r][1], 0, false);
        u = __builtin_amdgcn_cvt_pk_fp8_f32(acc[r][2], acc[r][3], u, true);
        Yb[row * 16 + tx] = u;  // row = 64 fp8 = 16 uint
      }
    }
  }
}

__global__ __launch_bounds__(256) void gemm128_kernel(const float* __restrict__ x, const float* __restrict__ W1,
                                                      const float* __restrict__ atts, const float* __restrict__ attd,
                                                      unsigned* __restrict__ h1b, float* __restrict__ as1,
                                                      float* __restrict__ ad1) {
  gemm_body<128, false>(blockIdx.x, x, W1, atts, attd, h1b, as1, ad1);
}

__global__ __launch_bounds__(256) void gemm64_kernel(const unsigned* __restrict__ h1eb, const float* __restrict__ W2,
                                                     const float* __restrict__ atts, const float* __restrict__ attd,
                                                     unsigned* __restrict__ h2b, float* __restrict__ as2,
                                                     float* __restrict__ ad2) {
  gemm_body<64, true>(blockIdx.x, h1eb, W2, atts, attd, h2b, as2, ad2);
}

// ---------------- layer-1 gather, fused e-compute + denom; fp8 rows ----------------
__global__ __launch_bounds__(256) void agg1_kernel(const uint2* __restrict__ h1f8, const int* __restrict__ rowptr,
                                                   const int* __restrict__ col, const float* __restrict__ as1,
                                                   const float* __restrict__ ad1, const float4* __restrict__ b1v,
                                                   uint4* __restrict__ h1eb4) {
  int n = (blockIdx.x * 256 + threadIdx.x) >> 6;
  int lane = threadIdx.x & 63;
  int slot = lane >> 4;  // 0..3
  int fo = lane & 15;    // feats fo*8 .. fo*8+7
  int h = fo >> 2;       // head for these 8 feats
  int beg = rowptr[n], end = rowptr[n + 1];
  float adh = ad1[n * 4 + h];

  f32x2 acc2[4];
#pragma unroll
  for (int j = 0; j < 4; ++j) acc2[j] = (f32x2){0.f, 0.f};
  float esum = 0.f;

#define ACC_EDGE1(E)                                               \
  {                                                                \
    int src = col[E];                                              \
    float a = __expf(lrelu(as1[src * 4 + h] + adh));               \
    esum += a;                                                     \
    f32x2 av = {a, a};                                             \
    uint2 uu = h1f8[src * 16 + fo];                                \
    f32x2 p0 = __builtin_amdgcn_cvt_pk_f32_fp8(uu.x, false);       \
    f32x2 p1 = __builtin_amdgcn_cvt_pk_f32_fp8(uu.x, true);        \
    f32x2 p2 = __builtin_amdgcn_cvt_pk_f32_fp8(uu.y, false);       \
    f32x2 p3 = __builtin_amdgcn_cvt_pk_f32_fp8(uu.y, true);        \
    acc2[0] += av * p0; acc2[1] += av * p1;                        \
    acc2[2] += av * p2; acc2[3] += av * p3;                        \
  }

  int i = beg;
  for (; i + 16 <= end; i += 16) {
#pragma unroll
    for (int u = 0; u < 4; ++u) ACC_EDGE1(i + u * 4 + slot);
  }
  for (; i + 4 <= end; i += 4) ACC_EDGE1(i + slot);
  int rem = end - i;
  if (slot < rem) ACC_EDGE1(i + slot);
#undef ACC_EDGE1
  // self loop (slot 0 only)
  if (slot == 0) {
    float a = __expf(lrelu(as1[n * 4 + h] + adh));
    esum += a;
    f32x2 av = {a, a};
    uint2 uu = h1f8[n * 16 + fo];
    f32x2 p0 = __builtin_amdgcn_cvt_pk_f32_fp8(uu.x, false);
    f32x2 p1 = __builtin_amdgcn_cvt_pk_f32_fp8(uu.x, true);
    f32x2 p2 = __builtin_amdgcn_cvt_pk_f32_fp8(uu.y, false);
    f32x2 p3 = __builtin_amdgcn_cvt_pk_f32_fp8(uu.y, true);
    acc2[0] += av * p0; acc2[1] += av * p1;
    acc2[2] += av * p2; acc2[3] += av * p3;
  }
#pragma unroll
  for (int j = 0; j < 4; ++j) {
    acc2[j].x += __shfl_xor(acc2[j].x, 16);
    acc2[j].y += __shfl_xor(acc2[j].y, 16);
    acc2[j].x += __shfl_xor(acc2[j].x, 32);
    acc2[j].y += __shfl_xor(acc2[j].y, 32);
  }
  esum += __shfl_xor(esum, 16);
  esum += __shfl_xor(esum, 32);
  if (slot == 0) {
    float dsc = 1.f / esum;
    float4 b0 = b1v[fo * 2], b1 = b1v[fo * 2 + 1];
    float f0 = elu(acc2[0].x * dsc + b0.x), f1 = elu(acc2[0].y * dsc + b0.y);
    float f2 = elu(acc2[1].x * dsc + b0.z), f3 = elu(acc2[1].y * dsc + b0.w);
    float f4 = elu(acc2[2].x * dsc + b1.x), f5 = elu(acc2[2].y * dsc + b1.y);
    float f6 = elu(acc2[3].x * dsc + b1.z), f7 = elu(acc2[3].y * dsc + b1.w);
    uint4 o;
    o.x = pack2bf(f0, f1); o.y = pack2bf(f2, f3);
    o.z = pack2bf(f4, f5); o.w = pack2bf(f6, f7);
    h1eb4[n * 16 + fo] = o;  // h1e stays bf16 (feeds gemm64)
  }
}

// ---------------- layer-2 gather, fused e + denom + global add pool; fp8 rows ----------------
__global__ __launch_bounds__(256) void agg2_kernel(const uint2* __restrict__ h2f8, const int* __restrict__ rowptr,
                                                   const int* __restrict__ col, const float* __restrict__ as2,
                                                   const float* __restrict__ ad2, const float4* __restrict__ b2v,
                                                   float* __restrict__ pooled) {
  __shared__ float red[4][64];
  int n = (blockIdx.x * 256 + threadIdx.x) >> 6;
  int lane = threadIdx.x & 63;
  int wid = threadIdx.x >> 6;
  int slot = lane >> 3;  // 0..7
  int fo = lane & 7;     // feats fo*8 .. fo*8+7
  int beg = rowptr[n], end = rowptr[n + 1];
  float ad = ad2[n];

  f32x2 acc2[4];
#pragma unroll
  for (int j = 0; j < 4; ++j) acc2[j] = (f32x2){0.f, 0.f};
  float esum = 0.f;

#define ACC_EDGE2(E)                                               \
  {                                                                \
    int src = col[E];                                              \
    float a = __expf(lrelu(as2[src] + ad));                        \
    esum += a;                                                     \
    f32x2 av = {a, a};                                             \
    uint2 uu = h2f8[src * 8 + fo];                                 \
    f32x2 p0 = __builtin_amdgcn_cvt_pk_f32_fp8(uu.x, false);       \
    f32x2 p1 = __builtin_amdgcn_cvt_pk_f32_fp8(uu.x, true);        \
    f32x2 p2 = __builtin_amdgcn_cvt_pk_f32_fp8(uu.y, false);       \
    f32x2 p3 = __builtin_amdgcn_cvt_pk_f32_fp8(uu.y, true);        \
    acc2[0] += av * p0; acc2[1] += av * p1;                        \
    acc2[2] += av * p2; acc2[3] += av * p3;                        \
  }

  int i = beg;
  for (; i + 32 <= end; i += 32) {
#pragma unroll
    for (int u = 0; u < 4; ++u) ACC_EDGE2(i + u * 8 + slot);
  }
  for (; i + 8 <= end; i += 8) ACC_EDGE2(i + slot);
  int rem = end - i;
  if (slot < rem) ACC_EDGE2(i + slot);
#undef ACC_EDGE2
  // self loop
  if (slot == 0) {
    float a = __expf(lrelu(as2[n] + ad));
    esum += a;
    f32x2 av = {a, a};
    uint2 uu = h2f8[n * 8 + fo];
    f32x2 p0 = __builtin_amdgcn_cvt_pk_f32_fp8(uu.x, false);
    f32x2 p1 = __builtin_amdgcn_cvt_pk_f32_fp8(uu.x, true);
    f32x2 p2 = __builtin_amdgcn_cvt_pk_f32_fp8(uu.y, false);
    f32x2 p3 = __builtin_amdgcn_cvt_pk_f32_fp8(uu.y, true);
    acc2[0] += av * p0; acc2[1] += av * p1;
    acc2[2] += av * p2; acc2[3] += av * p3;
  }
#pragma unroll
  for (int j = 0; j < 4; ++j) {
#pragma unroll
    for (int off = 8; off <= 32; off <<= 1) {
      acc2[j].x += __shfl_xor(acc2[j].x, off);
      acc2[j].y += __shfl_xor(acc2[j].y, off);
    }
  }
  esum += __shfl_xor(esum, 8);
  esum += __shfl_xor(esum, 16);
  esum += __shfl_xor(esum, 32);
  if (slot == 0) {
    float dsc = 1.f / esum;
    float4 b0 = b2v[fo * 2], b1 = b2v[fo * 2 + 1];
    red[wid][fo * 8 + 0] = elu(acc2[0].x * dsc + b0.x);
    red[wid][fo * 8 + 1] = elu(acc2[0].y * dsc + b0.y);
    red[wid][fo * 8 + 2] = elu(acc2[1].x * dsc + b0.z);
    red[wid][fo * 8 + 3] = elu(acc2[1].y * dsc + b0.w);
    red[wid][fo * 8 + 4] = elu(acc2[2].x * dsc + b1.x);
    red[wid][fo * 8 + 5] = elu(acc2[2].y * dsc + b1.y);
    red[wid][fo * 8 + 6] = elu(acc2[3].x * dsc + b1.z);
    red[wid][fo * 8 + 7] = elu(acc2[3].y * dsc + b1.w);
  }
  __syncthreads();
  if (threadIdx.x < 64) {
    float sum = red[0][threadIdx.x] + red[1][threadIdx.x] + red[2][threadIdx.x] + red[3][threadIdx.x];
    atomicAdd(&pooled[(blockIdx.x & 63) * 64 + threadIdx.x], sum);
  }
}

// ---------------- final: reduce pooled stripes + pooled@Wl+bl ----------------
__global__ void final_kernel(const float* __restrict__ pooledS, const float* __restrict__ Wl,
                             const float* __restrict__ bl, float* __restrict__ out) {
  __shared__ float p[64];
  int t = threadIdx.x;
  float v = 0.f;
  for (int k = 0; k < 64; ++k) v += pooledS[k * 64 + t];
  p[t] = v;
  out[t] = v;
  __syncthreads();
  if (t < 2) {
    float s = bl[t];
    for (int k = 0; k < 64; ++k) s += p[k] * Wl[k * 2 + t];
    out[64 + t] = s;
  }
}

extern "C" void kernel_launch(void* const* d_in, const int* in_sizes, int n_in,
                              void* d_out, int out_size, void* d_ws, size_t ws_size,
                              hipStream_t stream) {
  (void)in_sizes; (void)n_in; (void)out_size; (void)ws_size;
  const float* x     = (const float*)d_in[0];
  const int*   ei    = (const int*)d_in[1];
  const float* W1    = (const float*)d_in[2];
  const float* atts1 = (const float*)d_in[3];
  const float* attd1 = (const float*)d_in[4];
  const float* b1    = (const float*)d_in[5];
  const float* W2    = (const float*)d_in[6];
  const float* atts2 = (const float*)d_in[7];
  const float* attd2 = (const float*)d_in[8];
  const float* b2    = (const float*)d_in[9];
  const float* Wl    = (const float*)d_in[10];
  const float* bl    = (const float*)d_in[11];
  float* out = (float*)d_out;

  char* w = (char*)d_ws;
  unsigned* h1b  = (unsigned*)w; w += (size_t)N_NODES * 128;      // 6.4 MB fp8
  unsigned* h1eb = (unsigned*)w; w += (size_t)N_NODES * 128 * 2;  // 12.8 MB bf16
  unsigned* h2b  = (unsigned*)w; w += (size_t)N_NODES * 64;       // 3.2 MB fp8
  float* as1  = (float*)w; w += (size_t)N_NODES * 16;
  float* ad1  = (float*)w; w += (size_t)N_NODES * 16;
  float* as2  = (float*)w; w += (size_t)N_NODES * 4;
  float* ad2  = (float*)w; w += (size_t)N_NODES * 4;
  float* pooled = (float*)w; w += 64 * 64 * 4;                    // 64 stripes x 64
  int* rowptrF = (int*)w; w += (size_t)(N_NODES + 1) * 4 + 12;
  int* col    = (int*)w; w += (size_t)N_EDGES * 4;
  int2* eb    = (int2*)w; w += (size_t)N_EDGES * 8;               // bucket-ordered (src,dst)
  int* bh     = (int*)w; w += (size_t)BH_SIZE * 4;
  int* bhP    = (int*)w; w += (size_t)BH_SIZE * 4;
  int* blocksum = (int*)w; w += 256 * 4;
  int* blockoff = (int*)w; w += 256 * 4;

  // zero pooled only (CSR build needs no pre-zeroed globals)
  (void)hipMemsetAsync(pooled, 0, 64 * 64 * 4, stream);

  // CSR build: 2-level LDS counting sort (no global atomics)
  hist1_kernel<<<P1_BLOCKS, 256, 0, stream>>>(ei, bh);
  scan_part_kernel<<<BH_SIZE / 256, 256, 0, stream>>>(bh, bhP, blocksum);
  scan_top_kernel<<<1, 256, 0, stream>>>(blocksum, blockoff);
  scatter1_kernel<<<P1_BLOCKS, 256, 0, stream>>>(ei, bhP, blockoff, eb);
  bucket_csr_kernel<<<NB, 256, 0, stream>>>(eb, blockoff, rowptrF, col);

  gemm128_kernel<<<GEMM_BLOCKS, 256, 0, stream>>>(x, W1, atts1, attd1, h1b, as1, ad1);
  agg1_kernel<<<N_NODES / 4, 256, 0, stream>>>((const uint2*)h1b, rowptrF, col, as1, ad1,
                                               (const float4*)b1, (uint4*)h1eb);

  gemm64_kernel<<<GEMM_BLOCKS, 256, 0, stream>>>(h1eb, W2, atts2, attd2, h2b, as2, ad2);
  agg2_kernel<<<N_NODES / 4, 256, 0, stream>>>((const uint2*)h2b, rowptrF, col, as2, ad2,
                                               (const float4*)b2, pooled);

  final_kernel<<<1, 64, 0, stream>>>(pooled, Wl, bl, out);
}